// Round 1
// baseline (1240.265 us; speedup 1.0000x reference)
//
#include <hip/hip_runtime.h>

#define BB 8
#define DD 512
#define LL 4096
#define NH 8
#define HD 64
#define SCALE 0.125f

// ---------- bf16 helpers (bit-level, round-to-nearest-even) ----------
static __device__ __forceinline__ float bf2f(unsigned short u) {
  union { float f; unsigned int i; } c; c.i = ((unsigned int)u) << 16; return c.f;
}
static __device__ __forceinline__ unsigned short f2bf(float f) {
  union { float f; unsigned int i; } c; c.f = f;
  unsigned int i = c.i;
  unsigned int r = (i + 0x7fffu + ((i >> 16) & 1u)) >> 16;
  return (unsigned short)r;
}

// ---------- block reductions ----------
static __device__ __forceinline__ float waveSum(float v) {
#pragma unroll
  for (int o = 32; o; o >>= 1) v += __shfl_down(v, o, 64);
  return v;
}
static __device__ __forceinline__ float waveMax(float v) {
#pragma unroll
  for (int o = 32; o; o >>= 1) v = fmaxf(v, __shfl_down(v, o, 64));
  return v;
}
static __device__ float blockSum(float v, float* red) {
  const int lane = threadIdx.x & 63, wid = threadIdx.x >> 6;
  const int nw = (int)(blockDim.x >> 6);
  v = waveSum(v);
  if (lane == 0) red[wid] = v;
  __syncthreads();
  if (wid == 0) {
    float t = (lane < nw) ? red[lane] : 0.f;
    t = waveSum(t);
    if (lane == 0) red[0] = t;
  }
  __syncthreads();
  float r = red[0];
  __syncthreads();
  return r;
}
static __device__ float blockMax(float v, float* red) {
  const int lane = threadIdx.x & 63, wid = threadIdx.x >> 6;
  const int nw = (int)(blockDim.x >> 6);
  v = waveMax(v);
  if (lane == 0) red[wid] = v;
  __syncthreads();
  if (wid == 0) {
    float t = (lane < nw) ? red[lane] : -1e30f;
    t = waveMax(t);
    if (lane == 0) red[0] = t;
  }
  __syncthreads();
  float r = red[0];
  __syncthreads();
  return r;
}

// ---------- fused QKV GEMM: Q/K/V[d,l] = sum_e W*[e,d] * X[e,l] ----------
// grid: (LL/64, DD/64, BB), block 256. 64x64 tile, K-step 16, 4x4 acc per thread x3.
__global__ __launch_bounds__(256) void qkv_gemm(
    const float* __restrict__ x, const float* __restrict__ Wq,
    const float* __restrict__ Wk, const float* __restrict__ Wv,
    unsigned short* __restrict__ qn, unsigned short* __restrict__ kn,
    unsigned short* __restrict__ vn) {
  const int b = blockIdx.z;
  const int m0 = blockIdx.y * 64;  // d
  const int n0 = blockIdx.x * 64;  // l
  const float* Xb = x + (size_t)b * DD * LL;

  __shared__ float Xs[16][64];
  __shared__ float Ws[3][16][64];

  const int tid = threadIdx.x;
  const int tx = tid & 15;        // n (l) group
  const int ty = tid >> 4;        // m (d) group
  const int lr = tid >> 4;        // load row in k-slab
  const int lc = (tid & 15) * 4;  // load col

  float acc[3][4][4];
#pragma unroll
  for (int a = 0; a < 3; a++)
#pragma unroll
    for (int i = 0; i < 4; i++)
#pragma unroll
      for (int j = 0; j < 4; j++) acc[a][i][j] = 0.f;

  for (int k0 = 0; k0 < DD; k0 += 16) {
    const float4 xv = *(const float4*)(Xb + (size_t)(k0 + lr) * LL + n0 + lc);
    const float4 wq = *(const float4*)(Wq + (size_t)(k0 + lr) * DD + m0 + lc);
    const float4 wk = *(const float4*)(Wk + (size_t)(k0 + lr) * DD + m0 + lc);
    const float4 wv = *(const float4*)(Wv + (size_t)(k0 + lr) * DD + m0 + lc);
    __syncthreads();
    *(float4*)&Xs[lr][lc] = xv;
    *(float4*)&Ws[0][lr][lc] = wq;
    *(float4*)&Ws[1][lr][lc] = wk;
    *(float4*)&Ws[2][lr][lc] = wv;
    __syncthreads();
#pragma unroll
    for (int kk = 0; kk < 16; kk++) {
      const float4 bx = *(const float4*)&Xs[kk][tx * 4];
      const float bj[4] = {bx.x, bx.y, bx.z, bx.w};
#pragma unroll
      for (int a = 0; a < 3; a++) {
        const float4 av = *(const float4*)&Ws[a][kk][ty * 4];
        const float ai[4] = {av.x, av.y, av.z, av.w};
#pragma unroll
        for (int i = 0; i < 4; i++)
#pragma unroll
          for (int j = 0; j < 4; j++)
            acc[a][i][j] = fmaf(ai[i], bj[j], acc[a][i][j]);
      }
    }
  }

  const size_t base = (size_t)b * DD * LL;
#pragma unroll
  for (int i = 0; i < 4; i++) {
    const int d = m0 + ty * 4 + i;
    const size_t off = base + (size_t)d * LL + n0 + tx * 4;
    ushort4 pq, pk, pv;
    pq.x = f2bf(acc[0][i][0]); pq.y = f2bf(acc[0][i][1]);
    pq.z = f2bf(acc[0][i][2]); pq.w = f2bf(acc[0][i][3]);
    pk.x = f2bf(acc[1][i][0]); pk.y = f2bf(acc[1][i][1]);
    pk.z = f2bf(acc[1][i][2]); pk.w = f2bf(acc[1][i][3]);
    pv.x = f2bf(acc[2][i][0]); pv.y = f2bf(acc[2][i][1]);
    pv.z = f2bf(acc[2][i][2]); pv.w = f2bf(acc[2][i][3]);
    *(ushort4*)(qn + off) = pq;
    *(ushort4*)(kn + off) = pk;
    *(ushort4*)(vn + off) = pv;
  }
}

// ---------- relay token QKV: qr/kr/vr[b,d] = sum_e y[b,e]*W[e,d] ----------
// grid: (DD/256, BB), block 256
__global__ __launch_bounds__(256) void relay_qkv(
    const float* __restrict__ y, const float* __restrict__ Wq,
    const float* __restrict__ Wk, const float* __restrict__ Wv,
    float* __restrict__ qr, float* __restrict__ kr, float* __restrict__ vr) {
  const int b = blockIdx.y;
  const int d = blockIdx.x * 256 + threadIdx.x;
  __shared__ float ys[DD];
  for (int i = threadIdx.x; i < DD; i += 256) ys[i] = y[b * DD + i];
  __syncthreads();
  float aq = 0.f, ak = 0.f, av = 0.f;
  for (int e = 0; e < DD; e++) {
    const float yv = ys[e];
    aq = fmaf(yv, Wq[(size_t)e * DD + d], aq);
    ak = fmaf(yv, Wk[(size_t)e * DD + d], ak);
    av = fmaf(yv, Wv[(size_t)e * DD + d], av);
  }
  qr[b * DD + d] = aq;
  kr[b * DD + d] = ak;
  vr[b * DD + d] = av;
}

// ---------- local window attention (windows l-1,l,l+1, relay) ----------
// grid: (LL/256, NH, BB), block 256, one thread per l
__global__ __launch_bounds__(256) void local_attn(
    const unsigned short* __restrict__ qn, const unsigned short* __restrict__ kn,
    const unsigned short* __restrict__ vn, const float* __restrict__ kr,
    const float* __restrict__ vr, unsigned short* __restrict__ att) {
  const int b = blockIdx.z, n = blockIdx.y;
  const int l = blockIdx.x * 256 + threadIdx.x;
  const size_t hb = ((size_t)b * DD + n * HD) * LL;
  const unsigned short* qb = qn + hb;
  const unsigned short* kb = kn + hb;
  const unsigned short* vb = vn + hb;
  const int rb = b * DD + n * HD;
  const bool has_m = (l > 0), has_p = (l < LL - 1);
  const int lm = has_m ? l - 1 : l, lp = has_p ? l + 1 : l;

  float s0 = 0.f, s1 = 0.f, s2 = 0.f, s3 = 0.f;
  for (int h = 0; h < HD; h++) {
    const size_t r = (size_t)h * LL;
    const float q = bf2f(qb[r + l]);
    const float k1 = bf2f(kb[r + l]);
    const float k0 = has_m ? bf2f(kb[r + lm]) : 0.f;
    const float k2 = has_p ? bf2f(kb[r + lp]) : 0.f;
    s0 = fmaf(q, k0, s0);
    s1 = fmaf(q, k1, s1);
    s2 = fmaf(q, k2, s2);
    s3 = fmaf(q, kr[rb + h], s3);
  }
  s0 *= SCALE; s1 *= SCALE; s2 *= SCALE; s3 *= SCALE;
  // zero-padded boundary keys contribute score EXACTLY 0 inside the softmax
  const float m = fmaxf(fmaxf(s0, s1), fmaxf(s2, s3));
  const float e0 = __expf(s0 - m), e1 = __expf(s1 - m);
  const float e2 = __expf(s2 - m), e3 = __expf(s3 - m);
  const float inv = 1.f / (e0 + e1 + e2 + e3);
  const float a0 = e0 * inv, a1 = e1 * inv, a2 = e2 * inv, a3 = e3 * inv;

  for (int h = 0; h < HD; h++) {
    const size_t r = (size_t)h * LL;
    const float v1 = bf2f(vb[r + l]);
    const float v0 = has_m ? bf2f(vb[r + lm]) : 0.f;
    const float v2 = has_p ? bf2f(vb[r + lp]) : 0.f;
    const float o = a0 * v0 + a1 * v1 + a2 * v2 + a3 * vr[rb + h];
    att[hb + r + l] = f2bf(o);
  }
}

// ---------- nodes GEMM: nodes[e,l] = sum_d att[d,l]*WOr[d,e] + bOr[e] ----------
// grid: (LL/64, DD/64, BB), block 256
__global__ __launch_bounds__(256) void nodes_gemm(
    const unsigned short* __restrict__ att, const float* __restrict__ Wo,
    const float* __restrict__ bo, float* __restrict__ out) {
  const int b = blockIdx.z;
  const int m0 = blockIdx.y * 64;  // e
  const int n0 = blockIdx.x * 64;  // l
  const unsigned short* Ab = att + (size_t)b * DD * LL;

  __shared__ float Xs[16][64];
  __shared__ float Ws[16][64];

  const int tid = threadIdx.x;
  const int tx = tid & 15;
  const int ty = tid >> 4;
  const int lr = tid >> 4;
  const int lc = (tid & 15) * 4;

  float acc[4][4];
#pragma unroll
  for (int i = 0; i < 4; i++)
#pragma unroll
    for (int j = 0; j < 4; j++) acc[i][j] = 0.f;

  for (int k0 = 0; k0 < DD; k0 += 16) {
    const ushort4 hv = *(const ushort4*)(Ab + (size_t)(k0 + lr) * LL + n0 + lc);
    const float4 wv = *(const float4*)(Wo + (size_t)(k0 + lr) * DD + m0 + lc);
    __syncthreads();
    Xs[lr][lc + 0] = bf2f(hv.x);
    Xs[lr][lc + 1] = bf2f(hv.y);
    Xs[lr][lc + 2] = bf2f(hv.z);
    Xs[lr][lc + 3] = bf2f(hv.w);
    *(float4*)&Ws[lr][lc] = wv;
    __syncthreads();
#pragma unroll
    for (int kk = 0; kk < 16; kk++) {
      const float4 bx = *(const float4*)&Xs[kk][tx * 4];
      const float bj[4] = {bx.x, bx.y, bx.z, bx.w};
      const float4 av = *(const float4*)&Ws[kk][ty * 4];
      const float ai[4] = {av.x, av.y, av.z, av.w};
#pragma unroll
      for (int i = 0; i < 4; i++)
#pragma unroll
        for (int j = 0; j < 4; j++)
          acc[i][j] = fmaf(ai[i], bj[j], acc[i][j]);
    }
  }

  const size_t base = (size_t)b * DD * LL;
#pragma unroll
  for (int i = 0; i < 4; i++) {
    const int e = m0 + ty * 4 + i;
    const float bias = bo[e];
    float4 o;
    o.x = acc[i][0] + bias; o.y = acc[i][1] + bias;
    o.z = acc[i][2] + bias; o.w = acc[i][3] + bias;
    *(float4*)(out + base + (size_t)e * LL + n0 + tx * 4) = o;
  }
}

// ---------- relay attention over all L+1 keys ----------
// grid: (NH, BB), block 1024
__global__ __launch_bounds__(1024) void relay_attn(
    const float* __restrict__ qr, const unsigned short* __restrict__ kn,
    const unsigned short* __restrict__ vn, const float* __restrict__ krr,
    const float* __restrict__ vrr, float* __restrict__ attr) {
  const int n = blockIdx.x, b = blockIdx.y;
  __shared__ float qs[HD];
  __shared__ float sv[LL + 1];
  __shared__ float red[17];
  const int tid = threadIdx.x;
  const int rb = b * DD + n * HD;
  if (tid < HD) qs[tid] = qr[rb + tid];
  __syncthreads();
  const size_t hb = ((size_t)b * DD + n * HD) * LL;
  const unsigned short* kb = kn + hb;
  const unsigned short* vb = vn + hb;

  for (int l = tid; l <= LL; l += 1024) {
    float s = 0.f;
    if (l < LL) {
      for (int h = 0; h < HD; h++) s = fmaf(qs[h], bf2f(kb[(size_t)h * LL + l]), s);
    } else {
      for (int h = 0; h < HD; h++) s = fmaf(qs[h], krr[rb + h], s);
    }
    sv[l] = s * SCALE;
  }
  __syncthreads();

  float m = -1e30f;
  for (int l = tid; l <= LL; l += 1024) m = fmaxf(m, sv[l]);
  m = blockMax(m, red);

  float sum = 0.f;
  for (int l = tid; l <= LL; l += 1024) {
    const float p = __expf(sv[l] - m);
    sv[l] = p;
    sum += p;
  }
  sum = blockSum(sum, red);  // includes barriers; sv[] writes are visible after
  const float inv = 1.f / sum;

  for (int h = 0; h < HD; h++) {
    float a = 0.f;
    for (int l = tid; l <= LL; l += 1024)
      a = fmaf(sv[l], (l < LL) ? bf2f(vb[(size_t)h * LL + l]) : vrr[rb + h], a);
    a = blockSum(a, red);
    if (tid == 0) attr[rb + h] = a * inv;
  }
}

// ---------- relay projection: relay[b,e] = sum_d attr[b,d]*WOs[d,e] + bOs[e] ----------
// grid: (DD/256, BB), block 256
__global__ __launch_bounds__(256) void relay_proj(
    const float* __restrict__ attr, const float* __restrict__ Wstar,
    const float* __restrict__ bstar, float* __restrict__ out) {
  const int b = blockIdx.y;
  const int e = blockIdx.x * 256 + threadIdx.x;
  __shared__ float as[DD];
  for (int i = threadIdx.x; i < DD; i += 256) as[i] = attr[b * DD + i];
  __syncthreads();
  float acc = bstar[e];
  for (int d = 0; d < DD; d++) acc = fmaf(as[d], Wstar[(size_t)d * DD + e], acc);
  out[(size_t)BB * DD * LL + b * DD + e] = acc;
}

extern "C" void kernel_launch(void* const* d_in, const int* in_sizes, int n_in,
                              void* d_out, int out_size, void* d_ws, size_t ws_size,
                              hipStream_t stream) {
  const float* x   = (const float*)d_in[0];
  const float* y   = (const float*)d_in[1];
  const float* Wq  = (const float*)d_in[2];
  const float* Wk  = (const float*)d_in[3];
  const float* Wv  = (const float*)d_in[4];
  const float* WOr = (const float*)d_in[5];
  const float* bOr = (const float*)d_in[6];
  const float* WOs = (const float*)d_in[7];
  const float* bOs = (const float*)d_in[8];
  float* out = (float*)d_out;

  char* ws = (char*)d_ws;
  const size_t SZ = (size_t)BB * DD * LL * sizeof(unsigned short);  // 32 MiB
  unsigned short* qn  = (unsigned short*)(ws);
  unsigned short* kn  = (unsigned short*)(ws + SZ);
  unsigned short* vn  = (unsigned short*)(ws + 2 * SZ);
  unsigned short* att = (unsigned short*)(ws + 3 * SZ);
  float* qr   = (float*)(ws + 4 * SZ);
  float* kr   = qr + BB * DD;
  float* vr   = kr + BB * DD;
  float* attr = vr + BB * DD;

  qkv_gemm<<<dim3(LL / 64, DD / 64, BB), 256, 0, stream>>>(x, Wq, Wk, Wv, qn, kn, vn);
  relay_qkv<<<dim3(DD / 256, BB), 256, 0, stream>>>(y, Wq, Wk, Wv, qr, kr, vr);
  local_attn<<<dim3(LL / 256, NH, BB), 256, 0, stream>>>(qn, kn, vn, kr, vr, att);
  nodes_gemm<<<dim3(LL / 64, DD / 64, BB), 256, 0, stream>>>(att, WOr, bOr, out);
  relay_attn<<<dim3(NH, BB), 1024, 0, stream>>>(qr, kn, vn, kr, vr, attr);
  relay_proj<<<dim3(DD / 256, BB), 256, 0, stream>>>(attr, WOs, bOs, out);
}

// Round 2
// 589.323 us; speedup vs baseline: 2.1046x; 2.1046x over previous
//
#include <hip/hip_runtime.h>

#define BB 8
#define DD 512
#define LL 4096
#define NH 8
#define HD 64
#define SCALE 0.125f

typedef __attribute__((ext_vector_type(8))) short short8;
typedef __attribute__((ext_vector_type(4))) float f32x4;

// ---------- bf16 helpers (bit-level, round-to-nearest-even) ----------
static __device__ __forceinline__ float bf2f(unsigned short u) {
  union { float f; unsigned int i; } c; c.i = ((unsigned int)u) << 16; return c.f;
}
static __device__ __forceinline__ unsigned short f2bf(float f) {
  union { float f; unsigned int i; } c; c.f = f;
  unsigned int i = c.i;
  unsigned int r = (i + 0x7fffu + ((i >> 16) & 1u)) >> 16;
  return (unsigned short)r;
}

// async global->LDS, 16B per lane; lds base must be wave-uniform
static __device__ __forceinline__ void gload_lds16(const void* g, void* l) {
  __builtin_amdgcn_global_load_lds(
      (const __attribute__((address_space(1))) void*)g,
      (__attribute__((address_space(3))) void*)l, 16, 0, 0);
}

// ---------- block reductions ----------
static __device__ __forceinline__ float waveSum(float v) {
#pragma unroll
  for (int o = 32; o; o >>= 1) v += __shfl_down(v, o, 64);
  return v;
}
static __device__ __forceinline__ float waveMax(float v) {
#pragma unroll
  for (int o = 32; o; o >>= 1) v = fmaxf(v, __shfl_down(v, o, 64));
  return v;
}
static __device__ float blockSum(float v, float* red) {
  const int lane = threadIdx.x & 63, wid = threadIdx.x >> 6;
  const int nw = (int)(blockDim.x >> 6);
  v = waveSum(v);
  if (lane == 0) red[wid] = v;
  __syncthreads();
  if (wid == 0) {
    float t = (lane < nw) ? red[lane] : 0.f;
    t = waveSum(t);
    if (lane == 0) red[0] = t;
  }
  __syncthreads();
  float r = red[0];
  __syncthreads();
  return r;
}
static __device__ float blockMax(float v, float* red) {
  const int lane = threadIdx.x & 63, wid = threadIdx.x >> 6;
  const int nw = (int)(blockDim.x >> 6);
  v = waveMax(v);
  if (lane == 0) red[wid] = v;
  __syncthreads();
  if (wid == 0) {
    float t = (lane < nw) ? red[lane] : -1e30f;
    t = waveMax(t);
    if (lane == 0) red[0] = t;
  }
  __syncthreads();
  float r = red[0];
  __syncthreads();
  return r;
}

// ---------- transpose+cast W: in[K=512][M=512] f32 -> out[M][512] bf16 ----------
// grid (8,8), block 256
__global__ __launch_bounds__(256) void prep_w(
    const float* __restrict__ win, unsigned short* __restrict__ wout) {
  const int d0 = blockIdx.y * 64;  // in row (k)
  const int m0 = blockIdx.x * 64;  // in col (m) = out row
  __shared__ float t[64][65];
  const int tid = threadIdx.x;
  const int r = tid >> 4;
  const int c4 = (tid & 15) * 4;
#pragma unroll
  for (int p = 0; p < 4; p++) {
    const float4 v = *(const float4*)(win + (size_t)(d0 + p * 16 + r) * DD + m0 + c4);
    *(float4*)&t[p * 16 + r][c4] = v;
  }
  __syncthreads();
#pragma unroll
  for (int p = 0; p < 4; p++) {
    const int ll = p * 16 + r;
    ushort4 o;
    o.x = f2bf(t[c4 + 0][ll]);
    o.y = f2bf(t[c4 + 1][ll]);
    o.z = f2bf(t[c4 + 2][ll]);
    o.w = f2bf(t[c4 + 3][ll]);
    *(ushort4*)(wout + (size_t)(m0 + ll) * DD + d0 + c4) = o;
  }
}

// ---------- transpose+cast X: x[b][e=512][l=4096] f32 -> xt[b][l][e] bf16 ----------
// grid (64, 8, BB), block 256
__global__ __launch_bounds__(256) void prep_x(
    const float* __restrict__ x, unsigned short* __restrict__ xt) {
  const int b = blockIdx.z;
  const int e0 = blockIdx.y * 64;
  const int l0 = blockIdx.x * 64;
  __shared__ float t[64][65];
  const int tid = threadIdx.x;
  const int r = tid >> 4;
  const int c4 = (tid & 15) * 4;
  const float* xb = x + (size_t)b * DD * LL;
#pragma unroll
  for (int p = 0; p < 4; p++) {
    const float4 v = *(const float4*)(xb + (size_t)(e0 + p * 16 + r) * LL + l0 + c4);
    *(float4*)&t[p * 16 + r][c4] = v;
  }
  __syncthreads();
#pragma unroll
  for (int p = 0; p < 4; p++) {
    const int ll = p * 16 + r;
    ushort4 o;
    o.x = f2bf(t[c4 + 0][ll]);
    o.y = f2bf(t[c4 + 1][ll]);
    o.z = f2bf(t[c4 + 2][ll]);
    o.w = f2bf(t[c4 + 3][ll]);
    *(ushort4*)(xt + ((size_t)b * LL + l0 + ll) * DD + e0 + c4) = o;
  }
}

// ---------- fused QKV MFMA GEMM ----------
// C[m=0..1535][l] = sum_k Wt[m][k]*Xt[b][l][k]; m sector 0/1/2 -> q/k/n
// grid (LL/128=32, 1536/128=12, BB), block 256 (4 waves, 2x2)
__global__ __launch_bounds__(256) void qkv_mfma(
    const unsigned short* __restrict__ Wt, const unsigned short* __restrict__ Xt,
    unsigned short* __restrict__ qn, unsigned short* __restrict__ kn,
    unsigned short* __restrict__ vn) {
  const int b = blockIdx.z;
  const int m0 = blockIdx.y * 128;
  const int n0 = blockIdx.x * 128;
  __shared__ short As[128 * 32];
  __shared__ short Bs[128 * 32];
  const int tid = threadIdx.x;
  const int lane = tid & 63, w = tid >> 6;
  const int wm = w & 1, wn = w >> 1;

  const unsigned short* Ag = Wt + (size_t)m0 * DD;
  const unsigned short* Bg = Xt + ((size_t)b * LL + n0) * DD;
  const int srow = lane >> 2;
  const int scol = (lane & 3) * 8;

  f32x4 acc[4][4];
#pragma unroll
  for (int i = 0; i < 4; i++)
#pragma unroll
    for (int j = 0; j < 4; j++) acc[i][j] = (f32x4){0.f, 0.f, 0.f, 0.f};

  for (int k0 = 0; k0 < DD; k0 += 32) {
    __syncthreads();
#pragma unroll
    for (int p = 0; p < 2; p++) {
      const int c = w * 2 + p;
      gload_lds16(Ag + (size_t)(c * 16 + srow) * DD + k0 + scol, (short*)As + c * 16 * 32);
      gload_lds16(Bg + (size_t)(c * 16 + srow) * DD + k0 + scol, (short*)Bs + c * 16 * 32);
    }
    __syncthreads();
    short8 af[4], bfr[4];
#pragma unroll
    for (int i = 0; i < 4; i++)
      af[i] = *(const short8*)&As[(wm * 64 + i * 16 + (lane & 15)) * 32 + (lane >> 4) * 8];
#pragma unroll
    for (int j = 0; j < 4; j++)
      bfr[j] = *(const short8*)&Bs[(wn * 64 + j * 16 + (lane & 15)) * 32 + (lane >> 4) * 8];
#pragma unroll
    for (int i = 0; i < 4; i++)
#pragma unroll
      for (int j = 0; j < 4; j++)
        acc[i][j] = __builtin_amdgcn_mfma_f32_16x16x32_bf16(af[i], bfr[j], acc[i][j], 0, 0, 0);
  }

  const int sector = m0 >> 9;
  unsigned short* outp = (sector == 0) ? qn : ((sector == 1) ? kn : vn);
  outp += (size_t)b * DD * LL;
  const int dbase = (m0 & 511) + wm * 64;
  const int col0 = n0 + wn * 64 + (lane & 15);
#pragma unroll
  for (int i = 0; i < 4; i++) {
    const int dd0 = dbase + i * 16 + (lane >> 4) * 4;
#pragma unroll
    for (int j = 0; j < 4; j++) {
      const int cc = col0 + j * 16;
#pragma unroll
      for (int r = 0; r < 4; r++)
        outp[(size_t)(dd0 + r) * LL + cc] = f2bf(acc[i][j][r]);
    }
  }
}

// ---------- nodes MFMA GEMM: out[b][e][l] = sum_d WOrt[e][d]*att_t[b][l][d] + bo[e] ----------
// grid (32, 4, BB), block 256
__global__ __launch_bounds__(256) void nodes_mfma(
    const unsigned short* __restrict__ Wt, const unsigned short* __restrict__ At,
    const float* __restrict__ bo, float* __restrict__ out) {
  const int b = blockIdx.z;
  const int m0 = blockIdx.y * 128;
  const int n0 = blockIdx.x * 128;
  __shared__ short As[128 * 32];
  __shared__ short Bs[128 * 32];
  const int tid = threadIdx.x;
  const int lane = tid & 63, w = tid >> 6;
  const int wm = w & 1, wn = w >> 1;

  const unsigned short* Ag = Wt + (size_t)m0 * DD;
  const unsigned short* Bg = At + ((size_t)b * LL + n0) * DD;
  const int srow = lane >> 2;
  const int scol = (lane & 3) * 8;

  f32x4 acc[4][4];
#pragma unroll
  for (int i = 0; i < 4; i++)
#pragma unroll
    for (int j = 0; j < 4; j++) acc[i][j] = (f32x4){0.f, 0.f, 0.f, 0.f};

  for (int k0 = 0; k0 < DD; k0 += 32) {
    __syncthreads();
#pragma unroll
    for (int p = 0; p < 2; p++) {
      const int c = w * 2 + p;
      gload_lds16(Ag + (size_t)(c * 16 + srow) * DD + k0 + scol, (short*)As + c * 16 * 32);
      gload_lds16(Bg + (size_t)(c * 16 + srow) * DD + k0 + scol, (short*)Bs + c * 16 * 32);
    }
    __syncthreads();
    short8 af[4], bfr[4];
#pragma unroll
    for (int i = 0; i < 4; i++)
      af[i] = *(const short8*)&As[(wm * 64 + i * 16 + (lane & 15)) * 32 + (lane >> 4) * 8];
#pragma unroll
    for (int j = 0; j < 4; j++)
      bfr[j] = *(const short8*)&Bs[(wn * 64 + j * 16 + (lane & 15)) * 32 + (lane >> 4) * 8];
#pragma unroll
    for (int i = 0; i < 4; i++)
#pragma unroll
      for (int j = 0; j < 4; j++)
        acc[i][j] = __builtin_amdgcn_mfma_f32_16x16x32_bf16(af[i], bfr[j], acc[i][j], 0, 0, 0);
  }

  float* outp = out + (size_t)b * DD * LL;
  const int ebase = m0 + wm * 64;
  const int col0 = n0 + wn * 64 + (lane & 15);
#pragma unroll
  for (int i = 0; i < 4; i++) {
    const int e0 = ebase + i * 16 + (lane >> 4) * 4;
#pragma unroll
    for (int j = 0; j < 4; j++) {
      const int cc = col0 + j * 16;
#pragma unroll
      for (int r = 0; r < 4; r++)
        outp[(size_t)(e0 + r) * LL + cc] = acc[i][j][r] + bo[e0 + r];
    }
  }
}

// ---------- relay token QKV: qr/kr/vr[b,d] = sum_e y[b,e]*W[e,d] (f32) ----------
__global__ __launch_bounds__(256) void relay_qkv(
    const float* __restrict__ y, const float* __restrict__ Wq,
    const float* __restrict__ Wk, const float* __restrict__ Wv,
    float* __restrict__ qr, float* __restrict__ kr, float* __restrict__ vr) {
  const int b = blockIdx.y;
  const int d = blockIdx.x * 256 + threadIdx.x;
  __shared__ float ys[DD];
  for (int i = threadIdx.x; i < DD; i += 256) ys[i] = y[b * DD + i];
  __syncthreads();
  float aq = 0.f, ak = 0.f, av = 0.f;
  for (int e = 0; e < DD; e++) {
    const float yv = ys[e];
    aq = fmaf(yv, Wq[(size_t)e * DD + d], aq);
    ak = fmaf(yv, Wk[(size_t)e * DD + d], ak);
    av = fmaf(yv, Wv[(size_t)e * DD + d], av);
  }
  qr[b * DD + d] = aq;
  kr[b * DD + d] = ak;
  vr[b * DD + d] = av;
}

// ---------- local window attention; writes att_t[b][l][d] bf16 ----------
// grid: (LL/256, NH, BB), block 256, one thread per l
__global__ __launch_bounds__(256) void local_attn(
    const unsigned short* __restrict__ qn, const unsigned short* __restrict__ kn,
    const unsigned short* __restrict__ vn, const float* __restrict__ kr,
    const float* __restrict__ vr, unsigned short* __restrict__ att_t) {
  const int b = blockIdx.z, n = blockIdx.y;
  const int l = blockIdx.x * 256 + threadIdx.x;
  const size_t hb = ((size_t)b * DD + n * HD) * LL;
  const unsigned short* qb = qn + hb;
  const unsigned short* kb = kn + hb;
  const unsigned short* vb = vn + hb;
  const int rb = b * DD + n * HD;
  const bool has_m = (l > 0), has_p = (l < LL - 1);
  const int lm = has_m ? l - 1 : l, lp = has_p ? l + 1 : l;

  float s0 = 0.f, s1 = 0.f, s2 = 0.f, s3 = 0.f;
  for (int h = 0; h < HD; h++) {
    const size_t r = (size_t)h * LL;
    const float q = bf2f(qb[r + l]);
    const float k1 = bf2f(kb[r + l]);
    const float k0 = has_m ? bf2f(kb[r + lm]) : 0.f;
    const float k2 = has_p ? bf2f(kb[r + lp]) : 0.f;
    s0 = fmaf(q, k0, s0);
    s1 = fmaf(q, k1, s1);
    s2 = fmaf(q, k2, s2);
    s3 = fmaf(q, kr[rb + h], s3);
  }
  s0 *= SCALE; s1 *= SCALE; s2 *= SCALE; s3 *= SCALE;
  // zero-padded boundary keys contribute score EXACTLY 0 inside the softmax
  const float m = fmaxf(fmaxf(s0, s1), fmaxf(s2, s3));
  const float e0 = __expf(s0 - m), e1 = __expf(s1 - m);
  const float e2 = __expf(s2 - m), e3 = __expf(s3 - m);
  const float inv = 1.f / (e0 + e1 + e2 + e3);
  const float a0 = e0 * inv, a1 = e1 * inv, a2 = e2 * inv, a3 = e3 * inv;

  unsigned short* op = att_t + ((size_t)b * LL + l) * DD + n * HD;
#pragma unroll 4
  for (int h4 = 0; h4 < HD; h4 += 4) {
    float ov[4];
#pragma unroll
    for (int q = 0; q < 4; q++) {
      const int h = h4 + q;
      const size_t r = (size_t)h * LL;
      const float v1 = bf2f(vb[r + l]);
      const float v0 = has_m ? bf2f(vb[r + lm]) : 0.f;
      const float v2 = has_p ? bf2f(vb[r + lp]) : 0.f;
      ov[q] = a0 * v0 + a1 * v1 + a2 * v2 + a3 * vr[rb + h];
    }
    ushort4 pk;
    pk.x = f2bf(ov[0]); pk.y = f2bf(ov[1]);
    pk.z = f2bf(ov[2]); pk.w = f2bf(ov[3]);
    *(ushort4*)(op + h4) = pk;
  }
}

// ---------- relay attention over all L+1 keys ----------
// grid: (NH, BB), block 1024
__global__ __launch_bounds__(1024) void relay_attn(
    const float* __restrict__ qr, const unsigned short* __restrict__ kn,
    const unsigned short* __restrict__ vn, const float* __restrict__ krr,
    const float* __restrict__ vrr, float* __restrict__ attr) {
  const int n = blockIdx.x, b = blockIdx.y;
  __shared__ float qs[HD];
  __shared__ float sv[LL + 1];
  __shared__ float red[17];
  const int tid = threadIdx.x;
  const int rb = b * DD + n * HD;
  if (tid < HD) qs[tid] = qr[rb + tid];
  __syncthreads();
  const size_t hb = ((size_t)b * DD + n * HD) * LL;
  const unsigned short* kb = kn + hb;
  const unsigned short* vb = vn + hb;

  for (int l = tid; l <= LL; l += 1024) {
    float s = 0.f;
    if (l < LL) {
      for (int h = 0; h < HD; h++) s = fmaf(qs[h], bf2f(kb[(size_t)h * LL + l]), s);
    } else {
      for (int h = 0; h < HD; h++) s = fmaf(qs[h], krr[rb + h], s);
    }
    sv[l] = s * SCALE;
  }
  __syncthreads();

  float m = -1e30f;
  for (int l = tid; l <= LL; l += 1024) m = fmaxf(m, sv[l]);
  m = blockMax(m, red);

  float sum = 0.f;
  for (int l = tid; l <= LL; l += 1024) {
    const float p = __expf(sv[l] - m);
    sv[l] = p;
    sum += p;
  }
  sum = blockSum(sum, red);
  const float inv = 1.f / sum;

  for (int h = 0; h < HD; h++) {
    float a = 0.f;
    for (int l = tid; l <= LL; l += 1024)
      a = fmaf(sv[l], (l < LL) ? bf2f(vb[(size_t)h * LL + l]) : vrr[rb + h], a);
    a = blockSum(a, red);
    if (tid == 0) attr[rb + h] = a * inv;
  }
}

// ---------- relay projection ----------
__global__ __launch_bounds__(256) void relay_proj(
    const float* __restrict__ attr, const float* __restrict__ Wstar,
    const float* __restrict__ bstar, float* __restrict__ out) {
  const int b = blockIdx.y;
  const int e = blockIdx.x * 256 + threadIdx.x;
  __shared__ float as[DD];
  for (int i = threadIdx.x; i < DD; i += 256) as[i] = attr[b * DD + i];
  __syncthreads();
  float acc = bstar[e];
  for (int d = 0; d < DD; d++) acc = fmaf(as[d], Wstar[(size_t)d * DD + e], acc);
  out[(size_t)BB * DD * LL + b * DD + e] = acc;
}

extern "C" void kernel_launch(void* const* d_in, const int* in_sizes, int n_in,
                              void* d_out, int out_size, void* d_ws, size_t ws_size,
                              hipStream_t stream) {
  const float* x   = (const float*)d_in[0];
  const float* y   = (const float*)d_in[1];
  const float* Wq  = (const float*)d_in[2];
  const float* Wk  = (const float*)d_in[3];
  const float* Wv  = (const float*)d_in[4];
  const float* WOr = (const float*)d_in[5];
  const float* bOr = (const float*)d_in[6];
  const float* WOs = (const float*)d_in[7];
  const float* bOs = (const float*)d_in[8];
  float* out = (float*)d_out;

  char* ws = (char*)d_ws;
  const size_t SZ = (size_t)BB * DD * LL * sizeof(unsigned short);  // 32 MiB
  unsigned short* qn  = (unsigned short*)(ws);
  unsigned short* kn  = (unsigned short*)(ws + SZ);
  unsigned short* vn  = (unsigned short*)(ws + 2 * SZ);
  unsigned short* xt  = (unsigned short*)(ws + 3 * SZ);   // aliased: att_t after qkv_mfma
  unsigned short* att_t = xt;
  unsigned short* Wallt = (unsigned short*)(ws + 4 * SZ);              // 1536x512 bf16
  unsigned short* WOrt  = (unsigned short*)(ws + 4 * SZ + 1536 * 512 * 2);
  float* qr   = (float*)(ws + 4 * SZ + 2048 * 512 * 2);
  float* kr   = qr + BB * DD;
  float* vr   = kr + BB * DD;
  float* attr = vr + BB * DD;

  // weight transposes (bf16, k-contiguous rows)
  prep_w<<<dim3(8, 8), 256, 0, stream>>>(Wq, Wallt);
  prep_w<<<dim3(8, 8), 256, 0, stream>>>(Wk, Wallt + (size_t)512 * 512);
  prep_w<<<dim3(8, 8), 256, 0, stream>>>(Wv, Wallt + (size_t)1024 * 512);
  prep_w<<<dim3(8, 8), 256, 0, stream>>>(WOr, WOrt);
  prep_x<<<dim3(64, 8, BB), 256, 0, stream>>>(x, xt);

  qkv_mfma<<<dim3(32, 12, BB), 256, 0, stream>>>(Wallt, xt, qn, kn, vn);
  relay_qkv<<<dim3(DD / 256, BB), 256, 0, stream>>>(y, Wq, Wk, Wv, qr, kr, vr);
  local_attn<<<dim3(LL / 256, NH, BB), 256, 0, stream>>>(qn, kn, vn, kr, vr, att_t);
  nodes_mfma<<<dim3(32, 4, BB), 256, 0, stream>>>(WOrt, att_t, bOr, out);
  relay_attn<<<dim3(NH, BB), 1024, 0, stream>>>(qr, kn, vn, kr, vr, attr);
  relay_proj<<<dim3(DD / 256, BB), 256, 0, stream>>>(attr, WOs, bOs, out);
}

// Round 3
// 440.233 us; speedup vs baseline: 2.8173x; 1.3387x over previous
//
#include <hip/hip_runtime.h>

#define BB 8
#define DD 512
#define LL 4096
#define NH 8
#define HD 64
#define SCALE 0.125f
#define NCH 16
#define CH 256

typedef __attribute__((ext_vector_type(8))) short short8;
typedef __attribute__((ext_vector_type(4))) float f32x4;

// ---------- bf16 helpers (bit-level, round-to-nearest-even) ----------
static __device__ __forceinline__ float bf2f(unsigned short u) {
  union { float f; unsigned int i; } c; c.i = ((unsigned int)u) << 16; return c.f;
}
static __device__ __forceinline__ unsigned short f2bf(float f) {
  union { float f; unsigned int i; } c; c.f = f;
  unsigned int i = c.i;
  unsigned int r = (i + 0x7fffu + ((i >> 16) & 1u)) >> 16;
  return (unsigned short)r;
}

// async global->LDS, 16B per lane; lds base must be wave-uniform
static __device__ __forceinline__ void gload_lds16(const void* g, void* l) {
  __builtin_amdgcn_global_load_lds(
      (const __attribute__((address_space(1))) void*)g,
      (__attribute__((address_space(3))) void*)l, 16, 0, 0);
}

// ---------- reductions ----------
static __device__ __forceinline__ float waveSum(float v) {
#pragma unroll
  for (int o = 32; o; o >>= 1) v += __shfl_down(v, o, 64);
  return v;
}
static __device__ __forceinline__ float waveMax(float v) {
#pragma unroll
  for (int o = 32; o; o >>= 1) v = fmaxf(v, __shfl_down(v, o, 64));
  return v;
}
static __device__ float blockSum(float v, float* red) {
  const int lane = threadIdx.x & 63, wid = threadIdx.x >> 6;
  const int nw = (int)(blockDim.x >> 6);
  v = waveSum(v);
  if (lane == 0) red[wid] = v;
  __syncthreads();
  if (wid == 0) {
    float t = (lane < nw) ? red[lane] : 0.f;
    t = waveSum(t);
    if (lane == 0) red[0] = t;
  }
  __syncthreads();
  float r = red[0];
  __syncthreads();
  return r;
}
static __device__ float blockMax(float v, float* red) {
  const int lane = threadIdx.x & 63, wid = threadIdx.x >> 6;
  const int nw = (int)(blockDim.x >> 6);
  v = waveMax(v);
  if (lane == 0) red[wid] = v;
  __syncthreads();
  if (wid == 0) {
    float t = (lane < nw) ? red[lane] : -1e30f;
    t = waveMax(t);
    if (lane == 0) red[0] = t;
  }
  __syncthreads();
  float r = red[0];
  __syncthreads();
  return r;
}

// ---------- transpose+cast W: in[K=512][M=512] f32 -> out[M][512] bf16 ----------
__global__ __launch_bounds__(256) void prep_w(
    const float* __restrict__ win, unsigned short* __restrict__ wout) {
  const int d0 = blockIdx.y * 64;
  const int m0 = blockIdx.x * 64;
  __shared__ float t[64][65];
  const int tid = threadIdx.x;
  const int r = tid >> 4;
  const int c4 = (tid & 15) * 4;
#pragma unroll
  for (int p = 0; p < 4; p++) {
    const float4 v = *(const float4*)(win + (size_t)(d0 + p * 16 + r) * DD + m0 + c4);
    *(float4*)&t[p * 16 + r][c4] = v;
  }
  __syncthreads();
#pragma unroll
  for (int p = 0; p < 4; p++) {
    const int ll = p * 16 + r;
    ushort4 o;
    o.x = f2bf(t[c4 + 0][ll]);
    o.y = f2bf(t[c4 + 1][ll]);
    o.z = f2bf(t[c4 + 2][ll]);
    o.w = f2bf(t[c4 + 3][ll]);
    *(ushort4*)(wout + (size_t)(m0 + ll) * DD + d0 + c4) = o;
  }
}

// ---------- transpose+cast X: x[b][e][l] f32 -> xt[b][l][e] bf16 ----------
__global__ __launch_bounds__(256) void prep_x(
    const float* __restrict__ x, unsigned short* __restrict__ xt) {
  const int b = blockIdx.z;
  const int e0 = blockIdx.y * 64;
  const int l0 = blockIdx.x * 64;
  __shared__ float t[64][65];
  const int tid = threadIdx.x;
  const int r = tid >> 4;
  const int c4 = (tid & 15) * 4;
  const float* xb = x + (size_t)b * DD * LL;
#pragma unroll
  for (int p = 0; p < 4; p++) {
    const float4 v = *(const float4*)(xb + (size_t)(e0 + p * 16 + r) * LL + l0 + c4);
    *(float4*)&t[p * 16 + r][c4] = v;
  }
  __syncthreads();
#pragma unroll
  for (int p = 0; p < 4; p++) {
    const int ll = p * 16 + r;
    ushort4 o;
    o.x = f2bf(t[c4 + 0][ll]);
    o.y = f2bf(t[c4 + 1][ll]);
    o.z = f2bf(t[c4 + 2][ll]);
    o.w = f2bf(t[c4 + 3][ll]);
    *(ushort4*)(xt + ((size_t)b * LL + l0 + ll) * DD + e0 + c4) = o;
  }
}

// ---------- fused QKV MFMA GEMM ----------
// grid (32, 12, BB), block 256 (4 waves, 2x2)
__global__ __launch_bounds__(256) void qkv_mfma(
    const unsigned short* __restrict__ Wt, const unsigned short* __restrict__ Xt,
    unsigned short* __restrict__ qn, unsigned short* __restrict__ kn,
    unsigned short* __restrict__ vn) {
  const int b = blockIdx.z;
  const int m0 = blockIdx.y * 128;
  const int n0 = blockIdx.x * 128;
  __shared__ short As[128 * 32];
  __shared__ short Bs[128 * 32];
  const int tid = threadIdx.x;
  const int lane = tid & 63, w = tid >> 6;
  const int wm = w & 1, wn = w >> 1;

  const unsigned short* Ag = Wt + (size_t)m0 * DD;
  const unsigned short* Bg = Xt + ((size_t)b * LL + n0) * DD;
  const int srow = lane >> 2;
  const int scol = (lane & 3) * 8;

  f32x4 acc[4][4];
#pragma unroll
  for (int i = 0; i < 4; i++)
#pragma unroll
    for (int j = 0; j < 4; j++) acc[i][j] = (f32x4){0.f, 0.f, 0.f, 0.f};

  for (int k0 = 0; k0 < DD; k0 += 32) {
    __syncthreads();
#pragma unroll
    for (int p = 0; p < 2; p++) {
      const int c = w * 2 + p;
      gload_lds16(Ag + (size_t)(c * 16 + srow) * DD + k0 + scol, (short*)As + c * 16 * 32);
      gload_lds16(Bg + (size_t)(c * 16 + srow) * DD + k0 + scol, (short*)Bs + c * 16 * 32);
    }
    __syncthreads();
    short8 af[4], bfr[4];
#pragma unroll
    for (int i = 0; i < 4; i++)
      af[i] = *(const short8*)&As[(wm * 64 + i * 16 + (lane & 15)) * 32 + (lane >> 4) * 8];
#pragma unroll
    for (int j = 0; j < 4; j++)
      bfr[j] = *(const short8*)&Bs[(wn * 64 + j * 16 + (lane & 15)) * 32 + (lane >> 4) * 8];
#pragma unroll
    for (int i = 0; i < 4; i++)
#pragma unroll
      for (int j = 0; j < 4; j++)
        acc[i][j] = __builtin_amdgcn_mfma_f32_16x16x32_bf16(af[i], bfr[j], acc[i][j], 0, 0, 0);
  }

  const int sector = m0 >> 9;
  unsigned short* outp = (sector == 0) ? qn : ((sector == 1) ? kn : vn);
  outp += (size_t)b * DD * LL;
  const int dbase = (m0 & 511) + wm * 64;
  const int col0 = n0 + wn * 64 + (lane & 15);
#pragma unroll
  for (int i = 0; i < 4; i++) {
    const int dd0 = dbase + i * 16 + (lane >> 4) * 4;
#pragma unroll
    for (int j = 0; j < 4; j++) {
      const int cc = col0 + j * 16;
#pragma unroll
      for (int r = 0; r < 4; r++)
        outp[(size_t)(dd0 + r) * LL + cc] = f2bf(acc[i][j][r]);
    }
  }
}

// ---------- nodes MFMA GEMM ----------
// grid (32, 4, BB), block 256
__global__ __launch_bounds__(256) void nodes_mfma(
    const unsigned short* __restrict__ Wt, const unsigned short* __restrict__ At,
    const float* __restrict__ bo, float* __restrict__ out) {
  const int b = blockIdx.z;
  const int m0 = blockIdx.y * 128;
  const int n0 = blockIdx.x * 128;
  __shared__ short As[128 * 32];
  __shared__ short Bs[128 * 32];
  const int tid = threadIdx.x;
  const int lane = tid & 63, w = tid >> 6;
  const int wm = w & 1, wn = w >> 1;

  const unsigned short* Ag = Wt + (size_t)m0 * DD;
  const unsigned short* Bg = At + ((size_t)b * LL + n0) * DD;
  const int srow = lane >> 2;
  const int scol = (lane & 3) * 8;

  f32x4 acc[4][4];
#pragma unroll
  for (int i = 0; i < 4; i++)
#pragma unroll
    for (int j = 0; j < 4; j++) acc[i][j] = (f32x4){0.f, 0.f, 0.f, 0.f};

  for (int k0 = 0; k0 < DD; k0 += 32) {
    __syncthreads();
#pragma unroll
    for (int p = 0; p < 2; p++) {
      const int c = w * 2 + p;
      gload_lds16(Ag + (size_t)(c * 16 + srow) * DD + k0 + scol, (short*)As + c * 16 * 32);
      gload_lds16(Bg + (size_t)(c * 16 + srow) * DD + k0 + scol, (short*)Bs + c * 16 * 32);
    }
    __syncthreads();
    short8 af[4], bfr[4];
#pragma unroll
    for (int i = 0; i < 4; i++)
      af[i] = *(const short8*)&As[(wm * 64 + i * 16 + (lane & 15)) * 32 + (lane >> 4) * 8];
#pragma unroll
    for (int j = 0; j < 4; j++)
      bfr[j] = *(const short8*)&Bs[(wn * 64 + j * 16 + (lane & 15)) * 32 + (lane >> 4) * 8];
#pragma unroll
    for (int i = 0; i < 4; i++)
#pragma unroll
      for (int j = 0; j < 4; j++)
        acc[i][j] = __builtin_amdgcn_mfma_f32_16x16x32_bf16(af[i], bfr[j], acc[i][j], 0, 0, 0);
  }

  float* outp = out + (size_t)b * DD * LL;
  const int ebase = m0 + wm * 64;
  const int col0 = n0 + wn * 64 + (lane & 15);
#pragma unroll
  for (int i = 0; i < 4; i++) {
    const int e0 = ebase + i * 16 + (lane >> 4) * 4;
#pragma unroll
    for (int j = 0; j < 4; j++) {
      const int cc = col0 + j * 16;
#pragma unroll
      for (int r = 0; r < 4; r++)
        outp[(size_t)(e0 + r) * LL + cc] = acc[i][j][r] + bo[e0 + r];
    }
  }
}

// ---------- relay token QKV (f32 GEMV) ----------
__global__ __launch_bounds__(256) void relay_qkv(
    const float* __restrict__ y, const float* __restrict__ Wq,
    const float* __restrict__ Wk, const float* __restrict__ Wv,
    float* __restrict__ qr, float* __restrict__ kr, float* __restrict__ vr) {
  const int b = blockIdx.y;
  const int d = blockIdx.x * 256 + threadIdx.x;
  __shared__ float ys[DD];
  for (int i = threadIdx.x; i < DD; i += 256) ys[i] = y[b * DD + i];
  __syncthreads();
  float aq = 0.f, ak = 0.f, av = 0.f;
  for (int e = 0; e < DD; e++) {
    const float yv = ys[e];
    aq = fmaf(yv, Wq[(size_t)e * DD + d], aq);
    ak = fmaf(yv, Wk[(size_t)e * DD + d], ak);
    av = fmaf(yv, Wv[(size_t)e * DD + d], av);
  }
  qr[b * DD + d] = aq;
  kr[b * DD + d] = ak;
  vr[b * DD + d] = av;
}

// ---------- local window attention; writes att_t[b][l][d] bf16 ----------
__global__ __launch_bounds__(256) void local_attn(
    const unsigned short* __restrict__ qn, const unsigned short* __restrict__ kn,
    const unsigned short* __restrict__ vn, const float* __restrict__ kr,
    const float* __restrict__ vr, unsigned short* __restrict__ att_t) {
  const int b = blockIdx.z, n = blockIdx.y;
  const int l = blockIdx.x * 256 + threadIdx.x;
  const size_t hb = ((size_t)b * DD + n * HD) * LL;
  const unsigned short* qb = qn + hb;
  const unsigned short* kb = kn + hb;
  const unsigned short* vb = vn + hb;
  const int rb = b * DD + n * HD;
  const bool has_m = (l > 0), has_p = (l < LL - 1);
  const int lm = has_m ? l - 1 : l, lp = has_p ? l + 1 : l;

  float s0 = 0.f, s1 = 0.f, s2 = 0.f, s3 = 0.f;
  for (int h = 0; h < HD; h++) {
    const size_t r = (size_t)h * LL;
    const float q = bf2f(qb[r + l]);
    const float k1 = bf2f(kb[r + l]);
    const float k0 = has_m ? bf2f(kb[r + lm]) : 0.f;
    const float k2 = has_p ? bf2f(kb[r + lp]) : 0.f;
    s0 = fmaf(q, k0, s0);
    s1 = fmaf(q, k1, s1);
    s2 = fmaf(q, k2, s2);
    s3 = fmaf(q, kr[rb + h], s3);
  }
  s0 *= SCALE; s1 *= SCALE; s2 *= SCALE; s3 *= SCALE;
  const float m = fmaxf(fmaxf(s0, s1), fmaxf(s2, s3));
  const float e0 = __expf(s0 - m), e1 = __expf(s1 - m);
  const float e2 = __expf(s2 - m), e3 = __expf(s3 - m);
  const float inv = 1.f / (e0 + e1 + e2 + e3);
  const float a0 = e0 * inv, a1 = e1 * inv, a2 = e2 * inv, a3 = e3 * inv;

  unsigned short* op = att_t + ((size_t)b * LL + l) * DD + n * HD;
#pragma unroll 4
  for (int h4 = 0; h4 < HD; h4 += 4) {
    float ov[4];
#pragma unroll
    for (int q = 0; q < 4; q++) {
      const int h = h4 + q;
      const size_t r = (size_t)h * LL;
      const float v1 = bf2f(vb[r + l]);
      const float v0 = has_m ? bf2f(vb[r + lm]) : 0.f;
      const float v2 = has_p ? bf2f(vb[r + lp]) : 0.f;
      ov[q] = a0 * v0 + a1 * v1 + a2 * v2 + a3 * vr[rb + h];
    }
    ushort4 pk;
    pk.x = f2bf(ov[0]); pk.y = f2bf(ov[1]);
    pk.z = f2bf(ov[2]); pk.w = f2bf(ov[3]);
    *(ushort4*)(op + h4) = pk;
  }
}

// ---------- relay attention pass 1: chunk partials ----------
// grid (NCH, NH, BB), block 256 (4 waves); chunk = 256 l values
// partials per (b,n,ch): o[64], m, sum  (stride 68 floats)
__global__ __launch_bounds__(256) void relay_attn_part(
    const float* __restrict__ qr, const unsigned short* __restrict__ kn,
    const unsigned short* __restrict__ vn, float* __restrict__ part) {
  const int ch = blockIdx.x, n = blockIdx.y, b = blockIdx.z;
  const int tid = threadIdx.x, lane = tid & 63, w = tid >> 6;
  __shared__ float qs[HD];
  __shared__ float red[17];
  __shared__ float os[4][HD];
  const int rb = b * DD + n * HD;
  if (tid < HD) qs[tid] = qr[rb + tid];
  __syncthreads();
  const size_t hb = ((size_t)b * DD + n * HD) * LL;
  const unsigned short* kb = kn + hb;
  const unsigned short* vb = vn + hb;
  const int l = ch * CH + tid;

  float s = 0.f;
#pragma unroll 8
  for (int h = 0; h < HD; h++) s = fmaf(qs[h], bf2f(kb[(size_t)h * LL + l]), s);
  s *= SCALE;
  const float m = blockMax(s, red);
  const float p = __expf(s - m);
  const float sum = blockSum(p, red);

  // o[h] = sum_l p_l * v[h,l]; wave w owns l-range [ch*CH + w*64, +64)
  const int lb = ch * CH + w * 64;
#pragma unroll 4
  for (int h = 0; h < HD; h++) {
    const float v = bf2f(vb[(size_t)h * LL + lb + lane]);
    const float t = waveSum(p * v);
    if (lane == 0) os[w][h] = t;
  }
  __syncthreads();
  float* po = part + (((size_t)b * NH + n) * NCH + ch) * 68;
  if (tid < HD) po[tid] = os[0][tid] + os[1][tid] + os[2][tid] + os[3][tid];
  if (tid == 64) { po[64] = m; po[65] = sum; }
}

// ---------- relay attention pass 2: combine chunks + relay token ----------
// grid (NH, BB), block 64
__global__ __launch_bounds__(64) void relay_attn_combine(
    const float* __restrict__ qr, const float* __restrict__ krr,
    const float* __restrict__ vrr, const float* __restrict__ part,
    float* __restrict__ attr) {
  const int n = blockIdx.x, b = blockIdx.y;
  const int h = threadIdx.x;
  const int rb = b * DD + n * HD;
  // relay-token score, broadcast to all lanes
  float t = qr[rb + h] * krr[rb + h];
  t = waveSum(t);
  const float s_r = __shfl(t, 0, 64) * SCALE;
  const float* po = part + (((size_t)b * NH + n) * NCH) * 68;
  float M = s_r;
#pragma unroll
  for (int c = 0; c < NCH; c++) M = fmaxf(M, po[c * 68 + 64]);
  float S = __expf(s_r - M);
  float o = S * vrr[rb + h];
#pragma unroll
  for (int c = 0; c < NCH; c++) {
    const float e = __expf(po[c * 68 + 64] - M);
    S = fmaf(po[c * 68 + 65], e, S);
    o = fmaf(po[c * 68 + h], e, o);
  }
  attr[rb + h] = o / S;
}

// ---------- relay projection ----------
__global__ __launch_bounds__(256) void relay_proj(
    const float* __restrict__ attr, const float* __restrict__ Wstar,
    const float* __restrict__ bstar, float* __restrict__ out) {
  const int b = blockIdx.y;
  const int e = blockIdx.x * 256 + threadIdx.x;
  __shared__ float as[DD];
  for (int i = threadIdx.x; i < DD; i += 256) as[i] = attr[b * DD + i];
  __syncthreads();
  float acc = bstar[e];
  for (int d = 0; d < DD; d++) acc = fmaf(as[d], Wstar[(size_t)d * DD + e], acc);
  out[(size_t)BB * DD * LL + b * DD + e] = acc;
}

extern "C" void kernel_launch(void* const* d_in, const int* in_sizes, int n_in,
                              void* d_out, int out_size, void* d_ws, size_t ws_size,
                              hipStream_t stream) {
  const float* x   = (const float*)d_in[0];
  const float* y   = (const float*)d_in[1];
  const float* Wq  = (const float*)d_in[2];
  const float* Wk  = (const float*)d_in[3];
  const float* Wv  = (const float*)d_in[4];
  const float* WOr = (const float*)d_in[5];
  const float* bOr = (const float*)d_in[6];
  const float* WOs = (const float*)d_in[7];
  const float* bOs = (const float*)d_in[8];
  float* out = (float*)d_out;

  char* ws = (char*)d_ws;
  const size_t SZ = (size_t)BB * DD * LL * sizeof(unsigned short);  // 32 MiB
  unsigned short* qn  = (unsigned short*)(ws);
  unsigned short* kn  = (unsigned short*)(ws + SZ);
  unsigned short* vn  = (unsigned short*)(ws + 2 * SZ);
  unsigned short* xt  = (unsigned short*)(ws + 3 * SZ);   // aliased: att_t after qkv_mfma
  unsigned short* att_t = xt;
  unsigned short* Wallt = (unsigned short*)(ws + 4 * SZ);              // 1536x512 bf16
  unsigned short* WOrt  = (unsigned short*)(ws + 4 * SZ + 1536 * 512 * 2);
  float* qr   = (float*)(ws + 4 * SZ + 2048 * 512 * 2);
  float* kr   = qr + BB * DD;
  float* vr   = kr + BB * DD;
  float* attr = vr + BB * DD;
  float* part = attr + BB * DD;   // BB*NH*NCH*68 floats ≈ 272 KB

  prep_w<<<dim3(8, 8), 256, 0, stream>>>(Wq, Wallt);
  prep_w<<<dim3(8, 8), 256, 0, stream>>>(Wk, Wallt + (size_t)512 * 512);
  prep_w<<<dim3(8, 8), 256, 0, stream>>>(Wv, Wallt + (size_t)1024 * 512);
  prep_w<<<dim3(8, 8), 256, 0, stream>>>(WOr, WOrt);
  prep_x<<<dim3(64, 8, BB), 256, 0, stream>>>(x, xt);

  qkv_mfma<<<dim3(32, 12, BB), 256, 0, stream>>>(Wallt, xt, qn, kn, vn);
  relay_qkv<<<dim3(DD / 256, BB), 256, 0, stream>>>(y, Wq, Wk, Wv, qr, kr, vr);
  local_attn<<<dim3(LL / 256, NH, BB), 256, 0, stream>>>(qn, kn, vn, kr, vr, att_t);
  nodes_mfma<<<dim3(32, 4, BB), 256, 0, stream>>>(WOrt, att_t, bOr, out);
  relay_attn_part<<<dim3(NCH, NH, BB), 256, 0, stream>>>(qr, kn, vn, part);
  relay_attn_combine<<<dim3(NH, BB), 64, 0, stream>>>(qr, kr, vr, part, attr);
  relay_proj<<<dim3(DD / 256, BB), 256, 0, stream>>>(attr, WOs, bOs, out);
}

// Round 4
// 319.967 us; speedup vs baseline: 3.8762x; 1.3759x over previous
//
#include <hip/hip_runtime.h>

#define BB 8
#define DD 512
#define LL 4096
#define NH 8
#define HD 64
#define SCALE 0.125f
#define NCH 16
#define CH 256

typedef __attribute__((ext_vector_type(8))) short short8;
typedef __attribute__((ext_vector_type(4))) float f32x4;

// ---------- bf16 helpers (bit-level, round-to-nearest-even) ----------
static __device__ __forceinline__ float bf2f(unsigned short u) {
  union { float f; unsigned int i; } c; c.i = ((unsigned int)u) << 16; return c.f;
}
static __device__ __forceinline__ unsigned short f2bf(float f) {
  union { float f; unsigned int i; } c; c.f = f;
  unsigned int i = c.i;
  unsigned int r = (i + 0x7fffu + ((i >> 16) & 1u)) >> 16;
  return (unsigned short)r;
}

// async global->LDS, 16B per lane; lds base must be wave-uniform
static __device__ __forceinline__ void gload_lds16(const void* g, void* l) {
  __builtin_amdgcn_global_load_lds(
      (const __attribute__((address_space(1))) void*)g,
      (__attribute__((address_space(3))) void*)l, 16, 0, 0);
}

// ---------- reductions ----------
static __device__ __forceinline__ float waveSum(float v) {
#pragma unroll
  for (int o = 32; o; o >>= 1) v += __shfl_down(v, o, 64);
  return v;
}
static __device__ __forceinline__ float waveMax(float v) {
#pragma unroll
  for (int o = 32; o; o >>= 1) v = fmaxf(v, __shfl_down(v, o, 64));
  return v;
}
static __device__ __forceinline__ float grp8Sum(float v) {
  v += __shfl_xor(v, 1, 8);
  v += __shfl_xor(v, 2, 8);
  v += __shfl_xor(v, 4, 8);
  return v;
}
static __device__ float blockSum(float v, float* red) {
  const int lane = threadIdx.x & 63, wid = threadIdx.x >> 6;
  const int nw = (int)(blockDim.x >> 6);
  v = waveSum(v);
  if (lane == 0) red[wid] = v;
  __syncthreads();
  if (wid == 0) {
    float t = (lane < nw) ? red[lane] : 0.f;
    t = waveSum(t);
    if (lane == 0) red[0] = t;
  }
  __syncthreads();
  float r = red[0];
  __syncthreads();
  return r;
}
static __device__ float blockMax(float v, float* red) {
  const int lane = threadIdx.x & 63, wid = threadIdx.x >> 6;
  const int nw = (int)(blockDim.x >> 6);
  v = waveMax(v);
  if (lane == 0) red[wid] = v;
  __syncthreads();
  if (wid == 0) {
    float t = (lane < nw) ? red[lane] : -1e30f;
    t = waveMax(t);
    if (lane == 0) red[0] = t;
  }
  __syncthreads();
  float r = red[0];
  __syncthreads();
  return r;
}

// ---------- transpose+cast W: in[K=512][M=512] f32 -> out[M][512] bf16 ----------
__global__ __launch_bounds__(256) void prep_w(
    const float* __restrict__ win, unsigned short* __restrict__ wout) {
  const int d0 = blockIdx.y * 64;
  const int m0 = blockIdx.x * 64;
  __shared__ float t[64][65];
  const int tid = threadIdx.x;
  const int r = tid >> 4;
  const int c4 = (tid & 15) * 4;
#pragma unroll
  for (int p = 0; p < 4; p++) {
    const float4 v = *(const float4*)(win + (size_t)(d0 + p * 16 + r) * DD + m0 + c4);
    *(float4*)&t[p * 16 + r][c4] = v;
  }
  __syncthreads();
#pragma unroll
  for (int p = 0; p < 4; p++) {
    const int ll = p * 16 + r;
    ushort4 o;
    o.x = f2bf(t[c4 + 0][ll]);
    o.y = f2bf(t[c4 + 1][ll]);
    o.z = f2bf(t[c4 + 2][ll]);
    o.w = f2bf(t[c4 + 3][ll]);
    *(ushort4*)(wout + (size_t)(m0 + ll) * DD + d0 + c4) = o;
  }
}

// ---------- transpose+cast X: x[b][e][l] f32 -> xt[b][l][e] bf16 ----------
__global__ __launch_bounds__(256) void prep_x(
    const float* __restrict__ x, unsigned short* __restrict__ xt) {
  const int b = blockIdx.z;
  const int e0 = blockIdx.y * 64;
  const int l0 = blockIdx.x * 64;
  __shared__ float t[64][65];
  const int tid = threadIdx.x;
  const int r = tid >> 4;
  const int c4 = (tid & 15) * 4;
  const float* xb = x + (size_t)b * DD * LL;
#pragma unroll
  for (int p = 0; p < 4; p++) {
    const float4 v = *(const float4*)(xb + (size_t)(e0 + p * 16 + r) * LL + l0 + c4);
    *(float4*)&t[p * 16 + r][c4] = v;
  }
  __syncthreads();
#pragma unroll
  for (int p = 0; p < 4; p++) {
    const int ll = p * 16 + r;
    ushort4 o;
    o.x = f2bf(t[c4 + 0][ll]);
    o.y = f2bf(t[c4 + 1][ll]);
    o.z = f2bf(t[c4 + 2][ll]);
    o.w = f2bf(t[c4 + 3][ll]);
    *(ushort4*)(xt + ((size_t)b * LL + l0 + ll) * DD + e0 + c4) = o;
  }
}

// ---------- fused QKV MFMA GEMM; outputs q/k/v in [b][l][d] bf16 ----------
// grid (32, 12, BB), block 256 (4 waves, 2x2)
__global__ __launch_bounds__(256) void qkv_mfma(
    const unsigned short* __restrict__ Wt, const unsigned short* __restrict__ Xt,
    unsigned short* __restrict__ qn, unsigned short* __restrict__ kn,
    unsigned short* __restrict__ vn) {
  const int b = blockIdx.z;
  const int m0 = blockIdx.y * 128;
  const int n0 = blockIdx.x * 128;
  __shared__ __align__(16) unsigned short smem[128 * 136];  // K-loop uses first 16KB
  short* As = (short*)smem;
  short* Bs = (short*)(smem + 128 * 32);
  const int tid = threadIdx.x;
  const int lane = tid & 63, w = tid >> 6;
  const int wm = w & 1, wn = w >> 1;

  const unsigned short* Ag = Wt + (size_t)m0 * DD;
  const unsigned short* Bg = Xt + ((size_t)b * LL + n0) * DD;
  const int srow = lane >> 2;
  const int scol = (lane & 3) * 8;

  f32x4 acc[4][4];
#pragma unroll
  for (int i = 0; i < 4; i++)
#pragma unroll
    for (int j = 0; j < 4; j++) acc[i][j] = (f32x4){0.f, 0.f, 0.f, 0.f};

  for (int k0 = 0; k0 < DD; k0 += 32) {
    __syncthreads();
#pragma unroll
    for (int p = 0; p < 2; p++) {
      const int c = w * 2 + p;
      gload_lds16(Ag + (size_t)(c * 16 + srow) * DD + k0 + scol, As + c * 16 * 32);
      gload_lds16(Bg + (size_t)(c * 16 + srow) * DD + k0 + scol, Bs + c * 16 * 32);
    }
    __syncthreads();
    short8 af[4], bfr[4];
#pragma unroll
    for (int i = 0; i < 4; i++)
      af[i] = *(const short8*)&As[(wm * 64 + i * 16 + (lane & 15)) * 32 + (lane >> 4) * 8];
#pragma unroll
    for (int j = 0; j < 4; j++)
      bfr[j] = *(const short8*)&Bs[(wn * 64 + j * 16 + (lane & 15)) * 32 + (lane >> 4) * 8];
#pragma unroll
    for (int i = 0; i < 4; i++)
#pragma unroll
      for (int j = 0; j < 4; j++)
        acc[i][j] = __builtin_amdgcn_mfma_f32_16x16x32_bf16(af[i], bfr[j], acc[i][j], 0, 0, 0);
  }

  // epilogue: stage C-tile [l(128)][d(128)] in LDS (row stride 136), coalesced store
  __syncthreads();
  const int lb = wn * 64 + (lane & 15);
  const int db = wm * 64 + ((lane >> 4) << 2);
#pragma unroll
  for (int i = 0; i < 4; i++)
#pragma unroll
    for (int j = 0; j < 4; j++) {
      ushort4 pk;
      pk.x = f2bf(acc[i][j][0]); pk.y = f2bf(acc[i][j][1]);
      pk.z = f2bf(acc[i][j][2]); pk.w = f2bf(acc[i][j][3]);
      *(ushort4*)&smem[(lb + j * 16) * 136 + db + i * 16] = pk;
    }
  __syncthreads();
  const int sector = m0 >> 9;
  unsigned short* outp = ((sector == 0) ? qn : ((sector == 1) ? kn : vn)) + (size_t)b * LL * DD;
  const int d0 = m0 & 511;
#pragma unroll
  for (int it = 0; it < 8; it++) {
    const int flat = it * 2048 + tid * 8;
    const int row = flat >> 7;
    const int col = flat & 127;
    const short8 vdat = *(const short8*)&smem[row * 136 + col];
    *(short8*)(outp + (size_t)(n0 + row) * DD + d0 + col) = vdat;
  }
}

// ---------- nodes MFMA GEMM: out[b][e][l] = sum_d WOrt[e][d]*att_t[b][l][d] + bo[e] ----------
// grid (32, 4, BB), block 256
__global__ __launch_bounds__(256) void nodes_mfma(
    const unsigned short* __restrict__ Wt, const unsigned short* __restrict__ At,
    const float* __restrict__ bo, float* __restrict__ out) {
  const int b = blockIdx.z;
  const int m0 = blockIdx.y * 128;
  const int n0 = blockIdx.x * 128;
  __shared__ short As[128 * 32];
  __shared__ short Bs[128 * 32];
  const int tid = threadIdx.x;
  const int lane = tid & 63, w = tid >> 6;
  const int wm = w & 1, wn = w >> 1;

  const unsigned short* Ag = Wt + (size_t)m0 * DD;
  const unsigned short* Bg = At + ((size_t)b * LL + n0) * DD;
  const int srow = lane >> 2;
  const int scol = (lane & 3) * 8;

  f32x4 acc[4][4];
#pragma unroll
  for (int i = 0; i < 4; i++)
#pragma unroll
    for (int j = 0; j < 4; j++) acc[i][j] = (f32x4){0.f, 0.f, 0.f, 0.f};

  for (int k0 = 0; k0 < DD; k0 += 32) {
    __syncthreads();
#pragma unroll
    for (int p = 0; p < 2; p++) {
      const int c = w * 2 + p;
      gload_lds16(Ag + (size_t)(c * 16 + srow) * DD + k0 + scol, (short*)As + c * 16 * 32);
      gload_lds16(Bg + (size_t)(c * 16 + srow) * DD + k0 + scol, (short*)Bs + c * 16 * 32);
    }
    __syncthreads();
    short8 af[4], bfr[4];
#pragma unroll
    for (int i = 0; i < 4; i++)
      af[i] = *(const short8*)&As[(wm * 64 + i * 16 + (lane & 15)) * 32 + (lane >> 4) * 8];
#pragma unroll
    for (int j = 0; j < 4; j++)
      bfr[j] = *(const short8*)&Bs[(wn * 64 + j * 16 + (lane & 15)) * 32 + (lane >> 4) * 8];
#pragma unroll
    for (int i = 0; i < 4; i++)
#pragma unroll
      for (int j = 0; j < 4; j++)
        acc[i][j] = __builtin_amdgcn_mfma_f32_16x16x32_bf16(af[i], bfr[j], acc[i][j], 0, 0, 0);
  }

  float* outp = out + (size_t)b * DD * LL;
  const int ebase = m0 + wm * 64;
  const int col0 = n0 + wn * 64 + (lane & 15);
#pragma unroll
  for (int i = 0; i < 4; i++) {
    const int e0 = ebase + i * 16 + (lane >> 4) * 4;
#pragma unroll
    for (int j = 0; j < 4; j++) {
      const int cc = col0 + j * 16;
#pragma unroll
      for (int r = 0; r < 4; r++)
        outp[(size_t)(e0 + r) * LL + cc] = acc[i][j][r] + bo[e0 + r];
    }
  }
}

// ---------- relay token QKV (f32 GEMV) ----------
__global__ __launch_bounds__(256) void relay_qkv(
    const float* __restrict__ y, const float* __restrict__ Wq,
    const float* __restrict__ Wk, const float* __restrict__ Wv,
    float* __restrict__ qr, float* __restrict__ kr, float* __restrict__ vr) {
  const int b = blockIdx.y;
  const int d = blockIdx.x * 256 + threadIdx.x;
  __shared__ float ys[DD];
  for (int i = threadIdx.x; i < DD; i += 256) ys[i] = y[b * DD + i];
  __syncthreads();
  float aq = 0.f, ak = 0.f, av = 0.f;
  for (int e = 0; e < DD; e++) {
    const float yv = ys[e];
    aq = fmaf(yv, Wq[(size_t)e * DD + d], aq);
    ak = fmaf(yv, Wk[(size_t)e * DD + d], ak);
    av = fmaf(yv, Wv[(size_t)e * DD + d], av);
  }
  qr[b * DD + d] = aq;
  kr[b * DD + d] = ak;
  vr[b * DD + d] = av;
}

// ---------- local window attention on [b][l][d] layout ----------
// grid (LL/32, NH, BB), block 256; 8 lanes per (l,head) row
__global__ __launch_bounds__(256) void local_attn(
    const unsigned short* __restrict__ qn, const unsigned short* __restrict__ kn,
    const unsigned short* __restrict__ vn, const float* __restrict__ kr,
    const float* __restrict__ vr, unsigned short* __restrict__ att_t) {
  const int b = blockIdx.z, n = blockIdx.y;
  const int tid = threadIdx.x;
  const int li = tid >> 3, dl = tid & 7;
  const int l = blockIdx.x * 32 + li;
  __shared__ float krs[HD], vrs[HD];
  const int rb = b * DD + n * HD;
  if (tid < HD) { krs[tid] = kr[rb + tid]; vrs[tid] = vr[rb + tid]; }
  __syncthreads();

  const size_t rowbase = ((size_t)b * LL + l) * DD + n * HD + dl * 8;
  const unsigned short* qp = qn + rowbase;
  const unsigned short* kp = kn + rowbase;
  const unsigned short* vp = vn + rowbase;
  const bool has_m = (l > 0), has_p = (l < LL - 1);
  const long moff = has_m ? -(long)DD : 0;
  const long poff = has_p ? (long)DD : 0;

  const short8 q8 = *(const short8*)qp;
  const short8 km8 = *(const short8*)(kp + moff);
  const short8 k08 = *(const short8*)kp;
  const short8 kp8 = *(const short8*)(kp + poff);

  float s0 = 0.f, s1 = 0.f, s2 = 0.f, s3 = 0.f;
  float qf[8];
#pragma unroll
  for (int j = 0; j < 8; j++) {
    qf[j] = bf2f((unsigned short)q8[j]);
    s0 = fmaf(qf[j], bf2f((unsigned short)km8[j]), s0);
    s1 = fmaf(qf[j], bf2f((unsigned short)k08[j]), s1);
    s2 = fmaf(qf[j], bf2f((unsigned short)kp8[j]), s2);
    s3 = fmaf(qf[j], krs[dl * 8 + j], s3);
  }
  s0 = grp8Sum(s0) * SCALE;
  s1 = grp8Sum(s1) * SCALE;
  s2 = grp8Sum(s2) * SCALE;
  s3 = grp8Sum(s3) * SCALE;
  // zero-padded boundary keys contribute score EXACTLY 0 inside the softmax
  if (!has_m) s0 = 0.f;
  if (!has_p) s2 = 0.f;
  const float m = fmaxf(fmaxf(s0, s1), fmaxf(s2, s3));
  const float e0 = __expf(s0 - m), e1 = __expf(s1 - m);
  const float e2 = __expf(s2 - m), e3 = __expf(s3 - m);
  const float inv = 1.f / (e0 + e1 + e2 + e3);
  const float a0 = has_m ? e0 * inv : 0.f;  // zero value vector at boundary
  const float a1 = e1 * inv;
  const float a2 = has_p ? e2 * inv : 0.f;
  const float a3 = e3 * inv;

  const short8 vm8 = *(const short8*)(vp + moff);
  const short8 v08 = *(const short8*)vp;
  const short8 vp8 = *(const short8*)(vp + poff);
  short8 o8;
#pragma unroll
  for (int j = 0; j < 8; j++) {
    float o = a0 * bf2f((unsigned short)vm8[j]) + a1 * bf2f((unsigned short)v08[j]) +
              a2 * bf2f((unsigned short)vp8[j]) + a3 * vrs[dl * 8 + j];
    o8[j] = (short)f2bf(o);
  }
  *(short8*)(att_t + rowbase) = o8;
}

// ---------- relay attention pass 1: chunk partials ([b][l][d] layout) ----------
// grid (NCH, NH, BB), block 256; partials per (b,n,ch): o[64], m, sum (stride 68)
__global__ __launch_bounds__(256) void relay_attn_part(
    const float* __restrict__ qr, const unsigned short* __restrict__ kn,
    const unsigned short* __restrict__ vn, float* __restrict__ part) {
  const int ch = blockIdx.x, n = blockIdx.y, b = blockIdx.z;
  const int tid = threadIdx.x;
  const int li = tid >> 3, dl = tid & 7;
  __shared__ float qs[HD];
  __shared__ float sv[CH];
  __shared__ float red[17];
  __shared__ float os[32][68];
  const int rb = b * DD + n * HD;
  if (tid < HD) qs[tid] = qr[rb + tid];
  __syncthreads();
  const size_t base = ((size_t)b * LL + ch * CH) * DD + n * HD + dl * 8;

#pragma unroll
  for (int it = 0; it < 8; it++) {
    const int lr2 = it * 32 + li;
    const short8 kc = *(const short8*)(kn + base + (size_t)lr2 * DD);
    float p = 0.f;
#pragma unroll
    for (int j = 0; j < 8; j++) p = fmaf(qs[dl * 8 + j], bf2f((unsigned short)kc[j]), p);
    p = grp8Sum(p);
    if (dl == 0) sv[lr2] = p * SCALE;
  }
  __syncthreads();
  const float s = sv[tid];
  const float m = blockMax(s, red);
  const float pp = __expf(s - m);
  sv[tid] = pp;
  const float sum = blockSum(pp, red);  // barriers make sv[] visible

  float oc[8];
#pragma unroll
  for (int j = 0; j < 8; j++) oc[j] = 0.f;
#pragma unroll
  for (int it = 0; it < 8; it++) {
    const int lr2 = it * 32 + li;
    const float p = sv[lr2];
    const short8 vc = *(const short8*)(vn + base + (size_t)lr2 * DD);
#pragma unroll
    for (int j = 0; j < 8; j++) oc[j] = fmaf(p, bf2f((unsigned short)vc[j]), oc[j]);
  }
#pragma unroll
  for (int j = 0; j < 8; j++) os[li][dl * 8 + j] = oc[j];
  __syncthreads();
  float* po = part + (((size_t)b * NH + n) * NCH + ch) * 68;
  if (tid < HD) {
    float t = 0.f;
#pragma unroll 8
    for (int g = 0; g < 32; g++) t += os[g][tid];
    po[tid] = t;
  }
  if (tid == 64) { po[64] = m; po[65] = sum; }
}

// ---------- relay attention pass 2: combine chunks + relay token ----------
// grid (NH, BB), block 64
__global__ __launch_bounds__(64) void relay_attn_combine(
    const float* __restrict__ qr, const float* __restrict__ krr,
    const float* __restrict__ vrr, const float* __restrict__ part,
    float* __restrict__ attr) {
  const int n = blockIdx.x, b = blockIdx.y;
  const int h = threadIdx.x;
  const int rb = b * DD + n * HD;
  float t = qr[rb + h] * krr[rb + h];
  t = waveSum(t);
  const float s_r = __shfl(t, 0, 64) * SCALE;
  const float* po = part + (((size_t)b * NH + n) * NCH) * 68;
  float M = s_r;
#pragma unroll
  for (int c = 0; c < NCH; c++) M = fmaxf(M, po[c * 68 + 64]);
  float S = __expf(s_r - M);
  float o = S * vrr[rb + h];
#pragma unroll
  for (int c = 0; c < NCH; c++) {
    const float e = __expf(po[c * 68 + 64] - M);
    S = fmaf(po[c * 68 + 65], e, S);
    o = fmaf(po[c * 68 + h], e, o);
  }
  attr[rb + h] = o / S;
}

// ---------- relay projection ----------
__global__ __launch_bounds__(256) void relay_proj(
    const float* __restrict__ attr, const float* __restrict__ Wstar,
    const float* __restrict__ bstar, float* __restrict__ out) {
  const int b = blockIdx.y;
  const int e = blockIdx.x * 256 + threadIdx.x;
  __shared__ float as[DD];
  for (int i = threadIdx.x; i < DD; i += 256) as[i] = attr[b * DD + i];
  __syncthreads();
  float acc = bstar[e];
  for (int d = 0; d < DD; d++) acc = fmaf(as[d], Wstar[(size_t)d * DD + e], acc);
  out[(size_t)BB * DD * LL + b * DD + e] = acc;
}

extern "C" void kernel_launch(void* const* d_in, const int* in_sizes, int n_in,
                              void* d_out, int out_size, void* d_ws, size_t ws_size,
                              hipStream_t stream) {
  const float* x   = (const float*)d_in[0];
  const float* y   = (const float*)d_in[1];
  const float* Wq  = (const float*)d_in[2];
  const float* Wk  = (const float*)d_in[3];
  const float* Wv  = (const float*)d_in[4];
  const float* WOr = (const float*)d_in[5];
  const float* bOr = (const float*)d_in[6];
  const float* WOs = (const float*)d_in[7];
  const float* bOs = (const float*)d_in[8];
  float* out = (float*)d_out;

  char* ws = (char*)d_ws;
  const size_t SZ = (size_t)BB * DD * LL * sizeof(unsigned short);  // 32 MiB
  unsigned short* qn  = (unsigned short*)(ws);       // [b][l][d]
  unsigned short* kn  = (unsigned short*)(ws + SZ);  // [b][l][d]
  unsigned short* vn  = (unsigned short*)(ws + 2 * SZ);
  unsigned short* xt  = (unsigned short*)(ws + 3 * SZ);   // aliased: att_t after qkv_mfma
  unsigned short* att_t = xt;
  unsigned short* Wallt = (unsigned short*)(ws + 4 * SZ);              // 1536x512 bf16
  unsigned short* WOrt  = (unsigned short*)(ws + 4 * SZ + 1536 * 512 * 2);
  float* qr   = (float*)(ws + 4 * SZ + 2048 * 512 * 2);
  float* kr   = qr + BB * DD;
  float* vr   = kr + BB * DD;
  float* attr = vr + BB * DD;
  float* part = attr + BB * DD;   // BB*NH*NCH*68 floats

  prep_w<<<dim3(8, 8), 256, 0, stream>>>(Wq, Wallt);
  prep_w<<<dim3(8, 8), 256, 0, stream>>>(Wk, Wallt + (size_t)512 * 512);
  prep_w<<<dim3(8, 8), 256, 0, stream>>>(Wv, Wallt + (size_t)1024 * 512);
  prep_w<<<dim3(8, 8), 256, 0, stream>>>(WOr, WOrt);
  prep_x<<<dim3(64, 8, BB), 256, 0, stream>>>(x, xt);

  qkv_mfma<<<dim3(32, 12, BB), 256, 0, stream>>>(Wallt, xt, qn, kn, vn);
  relay_qkv<<<dim3(DD / 256, BB), 256, 0, stream>>>(y, Wq, Wk, Wv, qr, kr, vr);
  local_attn<<<dim3(LL / 32, NH, BB), 256, 0, stream>>>(qn, kn, vn, kr, vr, att_t);
  nodes_mfma<<<dim3(32, 4, BB), 256, 0, stream>>>(WOrt, att_t, bOr, out);
  relay_attn_part<<<dim3(NCH, NH, BB), 256, 0, stream>>>(qr, kn, vn, part);
  relay_attn_combine<<<dim3(NH, BB), 64, 0, stream>>>(qr, kr, vr, part, attr);
  relay_proj<<<dim3(DD / 256, BB), 256, 0, stream>>>(attr, WOs, bOs, out);
}